// Round 2
// baseline (422.671 us; speedup 1.0000x reference)
//
#include <hip/hip_runtime.h>
#include <hip/hip_bf16.h>
#include <stdint.h>

// Problem constants
#define NB    64
#define LSEQ  510
#define DIN   768
#define L1S   128
#define KS    20
#define OUTF  300
#define EPSL  1e-5f

#define M1    (NB * L1S)          // 8192
#define MK    (NB * KS)           // 1280
#define MT    (M1 + MK)           // 9472

// Output layout (flat, in return order, fp32)
#define OFF_H1    0
#define OFF_SCORE (M1 * OUTF)                 // 2,457,600
#define OFF_HK    (2 * M1 * OUTF)             // 4,915,200
#define OFF_SK    (OFF_HK + MK * OUTF)        // 5,299,200

// ws layout: [0..3] int flag; [64..] float scores[MT]; [65536..] float pooled[MT*DIN]
#define WS_SCORES_OFF 64
#define WS_POOLED_OFF 65536

// ---------------------------------------------------------------------------
// Mask-representation detection (bool tensors have undocumented encoding).
// Mask rows are valid-prefix(0)/masked-suffix(1); scan first 8192 bytes:
//   int32 -> words {0,1};  uint8 -> 0x01010101-ish;  fp32 -> 0x3F800000;
//   bf16 -> 0x3F803F80 (and 0x3F800000 at boundaries; bf16 checked first).
__global__ void detect_mask_kernel(const unsigned int* __restrict__ p, int* flag) {
    __shared__ int f_bf16, f_f32, f_other;
    if (threadIdx.x == 0) { f_bf16 = 0; f_f32 = 0; f_other = 0; }
    __syncthreads();
    for (int i = threadIdx.x; i < 2048; i += blockDim.x) {
        unsigned int v = p[i];
        if (v <= 1u) continue;
        if (v == 0x3F803F80u)       atomicOr(&f_bf16, 1);
        else if (v == 0x3F800000u)  atomicOr(&f_f32, 1);
        else                        atomicOr(&f_other, 1);
    }
    __syncthreads();
    if (threadIdx.x == 0) {
        int f = 0;                       // default int32
        if (f_bf16)       f = 3;         // bf16
        else if (f_f32)   f = 2;         // fp32
        else if (f_other) f = 1;         // uint8
        *flag = f;
    }
}

__device__ inline bool mask_at(const void* m, int idx, int flag) {
    switch (flag) {
        case 1:  return ((const unsigned char*)m)[idx] != 0;
        case 2:  return ((const float*)m)[idx] != 0.0f;
        case 3:  return ((const unsigned short*)m)[idx] != 0;
        default: return ((const int*)m)[idx] != 0;
    }
}

// ---------------------------------------------------------------------------
// Span-mean pooling: one block per (branch, n, span).  g in [0, MT).
__global__ __launch_bounds__(256)
void pool_kernel(const float* __restrict__ t1,
                 const float* __restrict__ know,
                 const int* __restrict__ s1s, const int* __restrict__ s1e,
                 const int* __restrict__ kss, const int* __restrict__ kse,
                 float* __restrict__ pooled) {
    int g = blockIdx.x;
    const float* x;
    int n, s, e;
    if (g < M1) {
        n = g / L1S; int sp = g - n * L1S;
        x = t1; s = s1s[n * L1S + sp]; e = s1e[n * L1S + sp];
    } else {
        int gg = g - M1;
        n = gg / KS; int sp = gg - n * KS;
        x = know; s = kss[n * KS + sp]; e = kse[n * KS + sp];
    }
    if (s < 0) s = 0;
    if (e > LSEQ) e = LSEQ;
    int len = e - s; if (len < 1) len = 1;
    float inv = 1.0f / (float)len;
    const float* base = x + (size_t)n * LSEQ * DIN;
    for (int c = threadIdx.x; c < DIN; c += blockDim.x) {
        float acc = 0.f;
        for (int r = s; r < e; ++r)
            acc += base[(size_t)r * DIN + c];
        pooled[(size_t)g * DIN + c] = acc * inv;
    }
}

// ---------------------------------------------------------------------------
// Fused GEMM (pooled[MT,768] x W^T[768,300] + b) + LayerNorm + score head.
// BM=32 rows/block, full 300(->320) cols in registers, BK=32 K-tile.
// Thread map: tx = tid&63 (cols c = tx + 64*cc, cc<5), ty = tid>>6 (rows ty+4*rr).
#define BM 32
#define BK 32

__device__ inline float waveReduceSum(float v) {
#pragma unroll
    for (int off = 32; off > 0; off >>= 1) v += __shfl_xor(v, off, 64);
    return v;
}

__global__ __launch_bounds__(256)
void gemm_ln_kernel(const float* __restrict__ A,       // [MT, DIN]
                    const float* __restrict__ W,       // [OUTF, DIN]
                    const float* __restrict__ bias,    // [OUTF]
                    const float* __restrict__ gamma,   // [OUTF]
                    const float* __restrict__ beta,    // [OUTF]
                    const float* __restrict__ Wsc,     // [OUTF]
                    const float* __restrict__ bsc,     // [1]
                    float* __restrict__ out,
                    float* __restrict__ scores) {
    __shared__ float As[BK][BM + 1];        // [k][r]
    __shared__ float Ws[BK][321];           // [k][c], padded

    const int tid = threadIdx.x;
    const int tx  = tid & 63;
    const int ty  = tid >> 6;
    const int R0  = blockIdx.x * BM;

    float acc[8][5];
#pragma unroll
    for (int rr = 0; rr < 8; ++rr)
#pragma unroll
        for (int cc = 0; cc < 5; ++cc) acc[rr][cc] = 0.f;

    for (int k0 = 0; k0 < DIN; k0 += BK) {
        // A tile: 32x32
        for (int idx = tid; idx < BM * BK; idx += 256) {
            int r = idx >> 5, k = idx & 31;
            As[k][r] = A[(size_t)(R0 + r) * DIN + k0 + k];
        }
        // W tile: 300x32 (transposed into LDS), pad cols [300,320) with 0
        for (int idx = tid; idx < OUTF * BK; idx += 256) {
            int c = idx >> 5, k = idx & 31;
            Ws[k][c] = W[(size_t)c * DIN + k0 + k];
        }
        for (int idx = tid; idx < 20 * BK; idx += 256) {
            int c = 300 + (idx >> 5), k = idx & 31;
            Ws[k][c] = 0.f;
        }
        __syncthreads();
#pragma unroll
        for (int k = 0; k < BK; ++k) {
            float wv[5];
#pragma unroll
            for (int cc = 0; cc < 5; ++cc) wv[cc] = Ws[k][tx + 64 * cc];
#pragma unroll
            for (int rr = 0; rr < 8; ++rr) {
                float av = As[k][ty + 4 * rr];
#pragma unroll
                for (int cc = 0; cc < 5; ++cc) acc[rr][cc] += av * wv[cc];
            }
        }
        __syncthreads();
    }

    // Per-column epilogue constants
    float bv[5], gv[5], bev[5], wscv[5];
#pragma unroll
    for (int cc = 0; cc < 5; ++cc) {
        int c = tx + 64 * cc;
        if (c < OUTF) {
            bv[cc]   = bias[c];
            gv[cc]   = gamma[c];
            bev[cc]  = beta[c];
            wscv[cc] = Wsc[c];
        } else { bv[cc] = gv[cc] = bev[cc] = wscv[cc] = 0.f; }
    }
    float bs0 = bsc[0];

#pragma unroll
    for (int rr = 0; rr < 8; ++rr) {
        float tv[5];
        float s = 0.f;
#pragma unroll
        for (int cc = 0; cc < 5; ++cc) {
            int c = tx + 64 * cc;
            float v = (c < OUTF) ? (acc[rr][cc] + bv[cc]) : 0.f;
            tv[cc] = v; s += v;
        }
        s = waveReduceSum(s);
        float m = s * (1.0f / OUTF);
        float vs = 0.f;
#pragma unroll
        for (int cc = 0; cc < 5; ++cc) {
            int c = tx + 64 * cc;
            float d = (c < OUTF) ? (tv[cc] - m) : 0.f;
            vs += d * d;
        }
        vs = waveReduceSum(vs);
        float rstd = rsqrtf(vs * (1.0f / OUTF) + EPSL);

        int g = R0 + ty + 4 * rr;
        size_t off = (g < M1) ? (size_t)OFF_H1 + (size_t)g * OUTF
                              : (size_t)OFF_HK + (size_t)(g - M1) * OUTF;
        float sc = 0.f;
#pragma unroll
        for (int cc = 0; cc < 5; ++cc) {
            int c = tx + 64 * cc;
            if (c < OUTF) {
                float h = (tv[cc] - m) * rstd * gv[cc] + bev[cc];
                out[off + c] = h;
                sc += h * wscv[cc];
            }
        }
        sc = waveReduceSum(sc);
        if (tx == 0) scores[g] = sc + bs0;
    }
}

// ---------------------------------------------------------------------------
// Masked softmax + broadcast write.  Blocks 0..63: branch1 (128 spans, write
// score broadcast (128,300)).  Blocks 64..127: know (20 spans, write sk).
__global__ __launch_bounds__(256)
void softmax_kernel(const float* __restrict__ scores,
                    const void* __restrict__ m1,
                    const void* __restrict__ mk,
                    const int* __restrict__ flagp,
                    float* __restrict__ out) {
    const int flag = *flagp;
    const int b = blockIdx.x;
    const int tid = threadIdx.x;
    __shared__ float sh[L1S];
    __shared__ float pr[L1S];

    if (b < NB) {
        int n = b;
        if (tid < L1S) {
            float v = scores[n * L1S + tid];
            if (mask_at(m1, n * L1S + tid, flag)) v = -INFINITY;
            sh[tid] = v;
        }
        __syncthreads();
        if (tid == 0) {
            float mx = -INFINITY;
            for (int i = 0; i < L1S; ++i) mx = fmaxf(mx, sh[i]);
            float sum = 0.f;
            for (int i = 0; i < L1S; ++i) { float e = expf(sh[i] - mx); pr[i] = e; sum += e; }
            float inv = 1.0f / sum;
            for (int i = 0; i < L1S; ++i) pr[i] *= inv;
        }
        __syncthreads();
        const size_t base = (size_t)OFF_SCORE + (size_t)n * L1S * OUTF;
        for (int idx = tid; idx < L1S * OUTF; idx += blockDim.x) {
            int i = idx / OUTF;
            out[base + idx] = pr[i];
        }
    } else {
        int n = b - NB;
        if (tid == 0) {
            float v[KS];
            float mx = -INFINITY;
            for (int i = 0; i < KS; ++i) {
                float x = scores[M1 + n * KS + i];
                if (mask_at(mk, n * KS + i, flag)) x = -INFINITY;
                v[i] = x; mx = fmaxf(mx, x);
            }
            float sum = 0.f;
            for (int i = 0; i < KS; ++i) { v[i] = expf(v[i] - mx); sum += v[i]; }
            float inv = 1.0f / sum;
            for (int i = 0; i < KS; ++i)
                out[(size_t)OFF_SK + n * KS + i] = v[i] * inv;
        }
    }
}

// ---------------------------------------------------------------------------
extern "C" void kernel_launch(void* const* d_in, const int* in_sizes, int n_in,
                              void* d_out, int out_size, void* d_ws, size_t ws_size,
                              hipStream_t stream) {
    const float* t1   = (const float*)d_in[0];
    const float* know = (const float*)d_in[1];
    const int* s1s = (const int*)d_in[2];
    const int* s1e = (const int*)d_in[3];
    const void* m1 = d_in[4];
    const int* kss = (const int*)d_in[5];
    const int* kse = (const int*)d_in[6];
    const void* mk = d_in[7];
    const float* Wl  = (const float*)d_in[8];
    const float* bl  = (const float*)d_in[9];
    const float* gm  = (const float*)d_in[10];
    const float* bt  = (const float*)d_in[11];
    const float* Wsc = (const float*)d_in[12];
    const float* bsc = (const float*)d_in[13];
    float* out = (float*)d_out;

    char* ws = (char*)d_ws;
    int*   flag   = (int*)ws;
    float* scores = (float*)(ws + WS_SCORES_OFF);
    float* pooled = (float*)(ws + WS_POOLED_OFF);

    detect_mask_kernel<<<1, 256, 0, stream>>>((const unsigned int*)m1, flag);
    pool_kernel<<<MT, 256, 0, stream>>>(t1, know, s1s, s1e, kss, kse, pooled);
    gemm_ln_kernel<<<MT / BM, 256, 0, stream>>>(pooled, Wl, bl, gm, bt, Wsc, bsc,
                                                out, scores);
    softmax_kernel<<<2 * NB, 256, 0, stream>>>(scores, m1, mk, flag, out);
}

// Round 3
// 282.089 us; speedup vs baseline: 1.4984x; 1.4984x over previous
//
#include <hip/hip_runtime.h>
#include <hip/hip_bf16.h>
#include <stdint.h>

// Problem constants
#define NB    64
#define LSEQ  510
#define DIN   768
#define L1S   128
#define KS    20
#define OUTF  300
#define NPAD  320                 // padded out-features (5 x 64)
#define EPSL  1e-5f

#define M1    (NB * L1S)          // 8192
#define MK    (NB * KS)           // 1280
#define MT    (M1 + MK)           // 9472

// Output layout (flat, in return order, fp32)
#define OFF_H1    0
#define OFF_SCORE (M1 * OUTF)                 // 2,457,600
#define OFF_HK    (2 * M1 * OUTF)             // 4,915,200
#define OFF_SK    (OFF_HK + MK * OUTF)        // 5,299,200

// ws layout (bytes)
#define WS_FLAG    0
#define WS_SCORES  64            // float[MT]
#define WS_PROBS   40960         // float[64*128]
#define WS_WBF     81920         // ushort[320*768]  (bf16)
#define WS_POOLED  589824        // ushort[MT*768]   (bf16)

typedef short  short8_t  __attribute__((ext_vector_type(8)));
typedef float  float4v_t __attribute__((ext_vector_type(4)));
typedef unsigned short ushort4_t __attribute__((ext_vector_type(4)));

// ---------------------------------------------------------------------------
// Mask-representation detection (bool encoding undocumented). Scan the first
// 8192 bytes (valid under every candidate encoding of the (64,128) mask).
__global__ void detect_mask_kernel(const unsigned int* __restrict__ p, int* flag) {
    __shared__ int f_bf16, f_f32, f_other;
    if (threadIdx.x == 0) { f_bf16 = 0; f_f32 = 0; f_other = 0; }
    __syncthreads();
    for (int i = threadIdx.x; i < 2048; i += blockDim.x) {
        unsigned int v = p[i];
        if (v <= 1u) continue;
        if (v == 0x3F803F80u)       atomicOr(&f_bf16, 1);
        else if (v == 0x3F800000u)  atomicOr(&f_f32, 1);
        else                        atomicOr(&f_other, 1);
    }
    __syncthreads();
    if (threadIdx.x == 0) {
        int f = 0;
        if (f_bf16)       f = 3;
        else if (f_f32)   f = 2;
        else if (f_other) f = 1;
        *flag = f;
    }
}

__device__ inline bool mask_at(const void* m, int idx, int flag) {
    switch (flag) {
        case 1:  return ((const unsigned char*)m)[idx] != 0;
        case 2:  return ((const float*)m)[idx] != 0.0f;
        case 3:  return ((const unsigned short*)m)[idx] != 0;
        default: return ((const int*)m)[idx] != 0;
    }
}

// ---------------------------------------------------------------------------
// W (fp32 [300][768]) -> bf16 [320][768], rows 300..319 zero.
__global__ __launch_bounds__(256)
void wconv_kernel(const float* __restrict__ W, unsigned short* __restrict__ Wb) {
    int idx = blockIdx.x * 256 + threadIdx.x;     // 960 blocks covers 245760
    if (idx >= NPAD * DIN) return;
    int r = idx / DIN;
    float v = (r < OUTF) ? W[idx - (r - (r < OUTF ? 0 : 0)) * 0 + 0] : 0.f; // placeholder
    // (compute properly below)
    int c = idx - r * DIN;
    v = (r < OUTF) ? W[(size_t)r * DIN + c] : 0.f;
    __hip_bfloat16 b = __float2bfloat16(v);
    Wb[idx] = *(unsigned short*)&b;
}

// ---------------------------------------------------------------------------
// Span-mean pooling -> bf16. One wave per span. 768 cols = 192 float4;
// lane handles float4 indices lane, lane+64, lane+128.
__global__ __launch_bounds__(256)
void pool_kernel(const float* __restrict__ t1,
                 const float* __restrict__ know,
                 const int* __restrict__ s1s, const int* __restrict__ s1e,
                 const int* __restrict__ kss, const int* __restrict__ kse,
                 unsigned short* __restrict__ pooled) {
    const int wave = threadIdx.x >> 6;
    const int lane = threadIdx.x & 63;
    const int g = blockIdx.x * 4 + wave;          // 2368 blocks * 4 = 9472
    const float* x;
    int n, s, e;
    if (g < M1) {
        n = g >> 7;                                // /128
        x = t1;  s = s1s[g]; e = s1e[g];
    } else {
        int gg = g - M1;
        n = gg / KS;
        x = know; s = kss[gg]; e = kse[gg];
    }
    if (s < 0) s = 0;
    if (e > LSEQ) e = LSEQ;
    int len = e - s; if (len < 1) len = 1;
    const float inv = 1.0f / (float)len;
    const float4* base = (const float4*)(x + (size_t)n * LSEQ * DIN);

    unsigned short* orow = pooled + (size_t)g * DIN;
#pragma unroll
    for (int j = 0; j < 3; ++j) {
        int c4 = lane + j * 64;                   // float4 index within row
        float4 acc = make_float4(0.f, 0.f, 0.f, 0.f);
        for (int r = s; r < e; ++r) {
            float4 v = base[(size_t)r * (DIN / 4) + c4];
            acc.x += v.x; acc.y += v.y; acc.z += v.z; acc.w += v.w;
        }
        __hip_bfloat16 b0 = __float2bfloat16(acc.x * inv);
        __hip_bfloat16 b1 = __float2bfloat16(acc.y * inv);
        __hip_bfloat16 b2 = __float2bfloat16(acc.z * inv);
        __hip_bfloat16 b3 = __float2bfloat16(acc.w * inv);
        ushort4_t pk;
        pk.x = *(unsigned short*)&b0; pk.y = *(unsigned short*)&b1;
        pk.z = *(unsigned short*)&b2; pk.w = *(unsigned short*)&b3;
        *(ushort4_t*)(orow + c4 * 4) = pk;        // 8B store
    }
}

// ---------------------------------------------------------------------------
// MFMA GEMM + fused bias/LayerNorm/score.
// Block = 320 threads = 5 waves; block owns a 16-row m-tile (592 blocks);
// wave w owns cols [64w, 64w+64) as 4 accumulators of 16x16.
// Fragment layouts (gfx950 16x16x32 bf16):
//   A: lane -> row = lane&15, k = (lane>>4)*8 + j   (8 contiguous bf16)
//   B: lane -> col = lane&15, k = (lane>>4)*8 + j   (W is [out][in] row-major)
//   D: reg i -> row = (lane>>4)*4 + i, col = lane&15
__global__ __launch_bounds__(320)
void gemm_mfma_kernel(const unsigned short* __restrict__ Apool, // bf16 [MT][768]
                      const unsigned short* __restrict__ Wb,    // bf16 [320][768]
                      const float* __restrict__ bias,
                      const float* __restrict__ gamma,
                      const float* __restrict__ beta,
                      const float* __restrict__ Wsc,
                      const float* __restrict__ bsc,
                      float* __restrict__ out,
                      float* __restrict__ scores) {
    __shared__ float sC[16][NPAD + 1];

    const int tid  = threadIdx.x;
    const int wave = tid >> 6;            // 0..4
    const int lane = tid & 63;
    const int quad = lane >> 4;
    const int l16  = lane & 15;
    const int R0   = blockIdx.x * 16;

    const unsigned short* arow = Apool + (size_t)(R0 + l16) * DIN + quad * 8;
    const unsigned short* brow0 = Wb + (size_t)(wave * 64 + 0 * 16 + l16) * DIN + quad * 8;
    const unsigned short* brow1 = Wb + (size_t)(wave * 64 + 1 * 16 + l16) * DIN + quad * 8;
    const unsigned short* brow2 = Wb + (size_t)(wave * 64 + 2 * 16 + l16) * DIN + quad * 8;
    const unsigned short* brow3 = Wb + (size_t)(wave * 64 + 3 * 16 + l16) * DIN + quad * 8;

    float4v_t acc0 = {0.f, 0.f, 0.f, 0.f};
    float4v_t acc1 = {0.f, 0.f, 0.f, 0.f};
    float4v_t acc2 = {0.f, 0.f, 0.f, 0.f};
    float4v_t acc3 = {0.f, 0.f, 0.f, 0.f};

#pragma unroll 4
    for (int k0 = 0; k0 < DIN; k0 += 32) {
        short8_t a  = *(const short8_t*)(arow + k0);
        short8_t b0 = *(const short8_t*)(brow0 + k0);
        short8_t b1 = *(const short8_t*)(brow1 + k0);
        short8_t b2 = *(const short8_t*)(brow2 + k0);
        short8_t b3 = *(const short8_t*)(brow3 + k0);
        acc0 = __builtin_amdgcn_mfma_f32_16x16x32_bf16(a, b0, acc0, 0, 0, 0);
        acc1 = __builtin_amdgcn_mfma_f32_16x16x32_bf16(a, b1, acc1, 0, 0, 0);
        acc2 = __builtin_amdgcn_mfma_f32_16x16x32_bf16(a, b2, acc2, 0, 0, 0);
        acc3 = __builtin_amdgcn_mfma_f32_16x16x32_bf16(a, b3, acc3, 0, 0, 0);
    }

    // Dump C fragments to LDS: row = quad*4+i, col = wave*64 + j*16 + l16
#pragma unroll
    for (int i = 0; i < 4; ++i) {
        sC[quad * 4 + i][wave * 64 +  0 + l16] = acc0[i];
        sC[quad * 4 + i][wave * 64 + 16 + l16] = acc1[i];
        sC[quad * 4 + i][wave * 64 + 32 + l16] = acc2[i];
        sC[quad * 4 + i][wave * 64 + 48 + l16] = acc3[i];
    }
    __syncthreads();

    // Fused bias + LayerNorm + score.  Waves 0..3 handle 4 rows each.
    if (wave < 4) {
        const float bs0 = bsc[0];
#pragma unroll
        for (int rr = 0; rr < 4; ++rr) {
            const int r = wave * 4 + rr;
            const int g = R0 + r;
            // pass 1: mean
            float s = 0.f;
            float tv[5];
#pragma unroll
            for (int m = 0; m < 5; ++m) {
                int c = lane + 64 * m;
                float v = (c < OUTF) ? (sC[r][c] + bias[c]) : 0.f;
                tv[m] = v; s += v;
            }
#pragma unroll
            for (int off = 32; off > 0; off >>= 1) s += __shfl_xor(s, off, 64);
            const float mean = s * (1.0f / OUTF);
            // pass 2: variance
            float vs = 0.f;
#pragma unroll
            for (int m = 0; m < 5; ++m) {
                int c = lane + 64 * m;
                float d = (c < OUTF) ? (tv[m] - mean) : 0.f;
                vs += d * d;
            }
#pragma unroll
            for (int off = 32; off > 0; off >>= 1) vs += __shfl_xor(vs, off, 64);
            const float rstd = rsqrtf(vs * (1.0f / OUTF) + EPSL);
            // pass 3: write h, accumulate score
            const size_t off0 = (g < M1) ? (size_t)OFF_H1 + (size_t)g * OUTF
                                         : (size_t)OFF_HK + (size_t)(g - M1) * OUTF;
            float sc = 0.f;
#pragma unroll
            for (int m = 0; m < 5; ++m) {
                int c = lane + 64 * m;
                if (c < OUTF) {
                    float h = (tv[m] - mean) * rstd * gamma[c] + beta[c];
                    out[off0 + c] = h;
                    sc += h * Wsc[c];
                }
            }
#pragma unroll
            for (int off = 32; off > 0; off >>= 1) sc += __shfl_xor(sc, off, 64);
            if (lane == 0) scores[g] = sc + bs0;
        }
    }
}

// ---------------------------------------------------------------------------
// Masked softmax: 128 waves (32 blocks).  Waves 0..63: branch1 row -> probs ws.
// Waves 64..127: know row -> sk written directly to out.
__global__ __launch_bounds__(256)
void softmax_kernel(const float* __restrict__ scores,
                    const void* __restrict__ m1,
                    const void* __restrict__ mk,
                    const int* __restrict__ flagp,
                    float* __restrict__ probs,
                    float* __restrict__ out) {
    const int flag = *flagp;
    const int w = blockIdx.x * 4 + (threadIdx.x >> 6);
    const int lane = threadIdx.x & 63;

    if (w < NB) {
        const int n = w;
        float v0 = scores[n * L1S + lane];
        float v1 = scores[n * L1S + lane + 64];
        if (mask_at(m1, n * L1S + lane, flag))      v0 = -INFINITY;
        if (mask_at(m1, n * L1S + lane + 64, flag)) v1 = -INFINITY;
        float mx = fmaxf(v0, v1);
#pragma unroll
        for (int off = 32; off > 0; off >>= 1) mx = fmaxf(mx, __shfl_xor(mx, off, 64));
        float e0 = __expf(v0 - mx);
        float e1 = __expf(v1 - mx);
        float s = e0 + e1;
#pragma unroll
        for (int off = 32; off > 0; off >>= 1) s += __shfl_xor(s, off, 64);
        float inv = 1.0f / s;
        probs[n * L1S + lane]      = e0 * inv;
        probs[n * L1S + lane + 64] = e1 * inv;
    } else {
        const int n = w - NB;
        float v = -INFINITY;
        if (lane < KS) {
            v = scores[M1 + n * KS + lane];
            if (mask_at(mk, n * KS + lane, flag)) v = -INFINITY;
        }
        float mx = v;
#pragma unroll
        for (int off = 32; off > 0; off >>= 1) mx = fmaxf(mx, __shfl_xor(mx, off, 64));
        float e = (lane < KS) ? __expf(v - mx) : 0.f;
        float s = e;
#pragma unroll
        for (int off = 32; off > 0; off >>= 1) s += __shfl_xor(s, off, 64);
        if (lane < KS) out[(size_t)OFF_SK + n * KS + lane] = e / s;
    }
}

// ---------------------------------------------------------------------------
// Broadcast probs (64x128) -> out score region (64,128,300), float4 writes.
__global__ __launch_bounds__(256)
void bcast_kernel(const float* __restrict__ probs, float* __restrict__ out) {
    const int e0 = (blockIdx.x * 256 + threadIdx.x) * 4;   // 2400 blocks exact
    float4 v;
    v.x = probs[(e0 + 0) / OUTF];
    v.y = probs[(e0 + 1) / OUTF];
    v.z = probs[(e0 + 2) / OUTF];
    v.w = probs[(e0 + 3) / OUTF];
    *(float4*)(out + (size_t)OFF_SCORE + e0) = v;
}

// ---------------------------------------------------------------------------
extern "C" void kernel_launch(void* const* d_in, const int* in_sizes, int n_in,
                              void* d_out, int out_size, void* d_ws, size_t ws_size,
                              hipStream_t stream) {
    const float* t1   = (const float*)d_in[0];
    const float* know = (const float*)d_in[1];
    const int* s1s = (const int*)d_in[2];
    const int* s1e = (const int*)d_in[3];
    const void* m1 = d_in[4];
    const int* kss = (const int*)d_in[5];
    const int* kse = (const int*)d_in[6];
    const void* mk = d_in[7];
    const float* Wl  = (const float*)d_in[8];
    const float* bl  = (const float*)d_in[9];
    const float* gm  = (const float*)d_in[10];
    const float* bt  = (const float*)d_in[11];
    const float* Wsc = (const float*)d_in[12];
    const float* bsc = (const float*)d_in[13];
    float* out = (float*)d_out;

    char* ws = (char*)d_ws;
    int*            flag   = (int*)(ws + WS_FLAG);
    float*          scores = (float*)(ws + WS_SCORES);
    float*          probs  = (float*)(ws + WS_PROBS);
    unsigned short* Wb     = (unsigned short*)(ws + WS_WBF);
    unsigned short* pooled = (unsigned short*)(ws + WS_POOLED);

    detect_mask_kernel<<<1, 256, 0, stream>>>((const unsigned int*)m1, flag);
    wconv_kernel<<<(NPAD * DIN + 255) / 256, 256, 0, stream>>>(Wl, Wb);
    pool_kernel<<<MT / 4, 256, 0, stream>>>(t1, know, s1s, s1e, kss, kse, pooled);
    gemm_mfma_kernel<<<MT / 16, 320, 0, stream>>>(pooled, Wb, bl, gm, bt, Wsc, bsc,
                                                  out, scores);
    softmax_kernel<<<32, 256, 0, stream>>>(scores, m1, mk, flag, probs, out);
    bcast_kernel<<<(M1 * OUTF) / 1024, 256, 0, stream>>>(probs, out);
}

// Round 4
// 266.976 us; speedup vs baseline: 1.5832x; 1.0566x over previous
//
#include <hip/hip_runtime.h>
#include <hip/hip_bf16.h>
#include <stdint.h>

// Problem constants
#define NB    64
#define LSEQ  510
#define DIN   768
#define L1S   128
#define KS    20
#define OUTF  300
#define NPAD  320                 // padded out-features (5 x 64)
#define EPSL  1e-5f

#define M1    (NB * L1S)          // 8192
#define MK    (NB * KS)           // 1280
#define MT    (M1 + MK)           // 9472

// Output layout (flat, in return order, fp32)
#define OFF_H1    0
#define OFF_SCORE (M1 * OUTF)                 // 2,457,600
#define OFF_HK    (2 * M1 * OUTF)             // 4,915,200
#define OFF_SK    (OFF_HK + MK * OUTF)        // 5,299,200

// ws layout (bytes)
#define WS_FLAG    0
#define WS_SCORES  64            // float[MT]
#define WS_PROBS   40960         // float[64*128]
#define WS_WBF     81920         // ushort[320*768]  (bf16)

typedef short  short8_t  __attribute__((ext_vector_type(8)));
typedef float  float4v_t __attribute__((ext_vector_type(4)));
typedef unsigned short ushort4_t __attribute__((ext_vector_type(4)));

// LDS geometry for the fused kernel
#define SA_STRIDE 776            // shorts per A row (768 + 8 pad); 1552 B, 16B-aligned
#define SC_STRIDE 324            // floats per C row (320 + 4 pad)
#define LDS_BYTES 41984          // max( 16*1552 + span meta , 2*16*324*4 = 41472 )

// ---------------------------------------------------------------------------
// Mask-representation detection (bool encoding undocumented). Scan the first
// 8192 bytes (valid under every candidate encoding of the (64,128) mask).
__global__ void detect_mask_kernel(const unsigned int* __restrict__ p, int* flag) {
    __shared__ int f_bf16, f_f32, f_other;
    if (threadIdx.x == 0) { f_bf16 = 0; f_f32 = 0; f_other = 0; }
    __syncthreads();
    for (int i = threadIdx.x; i < 2048; i += blockDim.x) {
        unsigned int v = p[i];
        if (v <= 1u) continue;
        if (v == 0x3F803F80u)       atomicOr(&f_bf16, 1);
        else if (v == 0x3F800000u)  atomicOr(&f_f32, 1);
        else                        atomicOr(&f_other, 1);
    }
    __syncthreads();
    if (threadIdx.x == 0) {
        int f = 0;
        if (f_bf16)       f = 3;
        else if (f_f32)   f = 2;
        else if (f_other) f = 1;
        *flag = f;
    }
}

__device__ inline bool mask_at(const void* m, int idx, int flag) {
    switch (flag) {
        case 1:  return ((const unsigned char*)m)[idx] != 0;
        case 2:  return ((const float*)m)[idx] != 0.0f;
        case 3:  return ((const unsigned short*)m)[idx] != 0;
        default: return ((const int*)m)[idx] != 0;
    }
}

// ---------------------------------------------------------------------------
// W (fp32 [300][768]) -> bf16 [320][768], rows 300..319 zero.
__global__ __launch_bounds__(256)
void wconv_kernel(const float* __restrict__ W, unsigned short* __restrict__ Wb) {
    int idx = blockIdx.x * 256 + threadIdx.x;     // 960 blocks, exact cover
    if (idx >= NPAD * DIN) return;
    int r = idx / DIN;
    float v = (r < OUTF) ? W[idx] : 0.f;          // idx == r*DIN + c
    __hip_bfloat16 b = __float2bfloat16(v);
    Wb[idx] = *(unsigned short*)&b;
}

// ---------------------------------------------------------------------------
// Fused: span-mean pool (global fp32 -> LDS bf16) + MFMA GEMM (split-K x2)
// + bias/LayerNorm/score epilogue.
// Block: 640 threads = 10 waves, owns 16 rows (spans) x 320 cols x full K.
// Wave w: col group cg = w%5 (cols 64*cg..+64), K half kh = w/5.
// Fragment layouts (verified in round 3):
//   A: row = lane&15, k = (lane>>4)*8 + j   (8 contiguous bf16)
//   B: col = lane&15, k = (lane>>4)*8 + j   (W [out][in] row-major)
//   D: reg i -> row = (lane>>4)*4 + i, col = lane&15
__global__ __launch_bounds__(640, 5)
void fused_gemm_kernel(const float* __restrict__ t1,
                       const float* __restrict__ know,
                       const int* __restrict__ s1s, const int* __restrict__ s1e,
                       const int* __restrict__ kss, const int* __restrict__ kse,
                       const unsigned short* __restrict__ Wb,   // bf16 [320][768]
                       const float* __restrict__ bias,
                       const float* __restrict__ gamma,
                       const float* __restrict__ beta,
                       const float* __restrict__ Wsc,
                       const float* __restrict__ bsc,
                       float* __restrict__ out,
                       float* __restrict__ scores) {
    __shared__ unsigned long long lds_raw[LDS_BYTES / 8];
    unsigned short* sA   = (unsigned short*)lds_raw;            // [16][776]
    int*   sSrc = (int*)  ((char*)lds_raw + 16 * 1552);         // [16] float4 idx
    int*   sLen = (int*)  ((char*)lds_raw + 16 * 1552 + 64);    // [16]
    float* sInv = (float*)((char*)lds_raw + 16 * 1552 + 128);   // [16]

    const int tid = threadIdx.x;
    const int R0  = blockIdx.x * 16;
    const bool isk = (R0 >= M1);                 // uniform per block (512/80 split)

    // ---- span metadata ----
    if (tid < 16) {
        int g = R0 + tid;
        int s, e, n;
        if (!isk) { n = g >> 7;          s = s1s[g];      e = s1e[g]; }
        else      { int gg = g - M1; n = gg / KS; s = kss[gg]; e = kse[gg]; }
        if (s < 0) s = 0;
        if (e > LSEQ) e = LSEQ;
        int len = e - s; if (len < 1) len = 1;
        sSrc[tid] = n * (LSEQ * (DIN / 4)) + s * (DIN / 4);
        sLen[tid] = len;
        sInv[tid] = 1.0f / (float)len;
    }
    __syncthreads();

    // ---- pooling: 16 spans x 192 float4-cols = 3072 tasks ----
    const float4* src4 = (const float4*)(isk ? know : t1);
    for (int t = tid; t < 16 * 192; t += 640) {
        int sp = t / 192;
        int c4 = t - sp * 192;
        const float4* p = src4 + sSrc[sp] + c4;
        int len = sLen[sp];
        float4 acc = p[0];
        for (int r = 1; r < len; ++r) {
            float4 v = p[r * 192];
            acc.x += v.x; acc.y += v.y; acc.z += v.z; acc.w += v.w;
        }
        float inv = sInv[sp];
        __hip_bfloat16 b0 = __float2bfloat16(acc.x * inv);
        __hip_bfloat16 b1 = __float2bfloat16(acc.y * inv);
        __hip_bfloat16 b2 = __float2bfloat16(acc.z * inv);
        __hip_bfloat16 b3 = __float2bfloat16(acc.w * inv);
        ushort4_t pk;
        pk.x = *(unsigned short*)&b0; pk.y = *(unsigned short*)&b1;
        pk.z = *(unsigned short*)&b2; pk.w = *(unsigned short*)&b3;
        *(ushort4_t*)(sA + sp * SA_STRIDE + c4 * 4) = pk;
    }
    __syncthreads();

    // ---- MFMA GEMM, split-K ----
    const int wave = tid >> 6;            // 0..9
    const int lane = tid & 63;
    const int quad = lane >> 4;
    const int l16  = lane & 15;
    const int cg   = wave % 5;            // col group: cols [64cg, 64cg+64)
    const int kh   = wave / 5;            // K half: [384kh, 384kh+384)

    const unsigned short* sArow = sA + l16 * SA_STRIDE + quad * 8 + kh * 384;
    const unsigned short* bb = Wb + (size_t)(cg * 64 + l16) * DIN + quad * 8 + kh * 384;

    float4v_t acc0 = {0.f, 0.f, 0.f, 0.f};
    float4v_t acc1 = {0.f, 0.f, 0.f, 0.f};
    float4v_t acc2 = {0.f, 0.f, 0.f, 0.f};
    float4v_t acc3 = {0.f, 0.f, 0.f, 0.f};

#pragma unroll 4
    for (int k0 = 0; k0 < 384; k0 += 32) {
        short8_t a  = *(const short8_t*)(sArow + k0);
        short8_t b0 = *(const short8_t*)(bb + 0 * 16 * DIN + k0);
        short8_t b1 = *(const short8_t*)(bb + 1 * 16 * DIN + k0);
        short8_t b2 = *(const short8_t*)(bb + 2 * 16 * DIN + k0);
        short8_t b3 = *(const short8_t*)(bb + 3 * 16 * DIN + k0);
        acc0 = __builtin_amdgcn_mfma_f32_16x16x32_bf16(a, b0, acc0, 0, 0, 0);
        acc1 = __builtin_amdgcn_mfma_f32_16x16x32_bf16(a, b1, acc1, 0, 0, 0);
        acc2 = __builtin_amdgcn_mfma_f32_16x16x32_bf16(a, b2, acc2, 0, 0, 0);
        acc3 = __builtin_amdgcn_mfma_f32_16x16x32_bf16(a, b3, acc3, 0, 0, 0);
    }

    // ---- dump partials (sC aliases sA; all ds_reads of sA are complete) ----
    __syncthreads();
    float* sC = (float*)lds_raw;          // [2][16][SC_STRIDE]
#pragma unroll
    for (int i = 0; i < 4; ++i) {
        int r = (kh * 16 + quad * 4 + i) * SC_STRIDE + cg * 64 + l16;
        sC[r +  0] = acc0[i];
        sC[r + 16] = acc1[i];
        sC[r + 32] = acc2[i];
        sC[r + 48] = acc3[i];
    }
    __syncthreads();

    // ---- epilogue: bias + LayerNorm + score.  Waves 0..7, 2 rows each ----
    if (wave < 8) {
        const float bs0 = bsc[0];
#pragma unroll
        for (int rr = 0; rr < 2; ++rr) {
            const int r = wave * 2 + rr;
            const int g = R0 + r;
            float tv[5];
            float s = 0.f;
#pragma unroll
            for (int m = 0; m < 5; ++m) {
                int c = lane + 64 * m;
                float v = 0.f;
                if (c < OUTF)
                    v = sC[r * SC_STRIDE + c] + sC[(16 + r) * SC_STRIDE + c] + bias[c];
                tv[m] = v; s += v;
            }
#pragma unroll
            for (int off = 32; off > 0; off >>= 1) s += __shfl_xor(s, off, 64);
            const float mean = s * (1.0f / OUTF);
            float vs = 0.f;
#pragma unroll
            for (int m = 0; m < 5; ++m) {
                int c = lane + 64 * m;
                float d = (c < OUTF) ? (tv[m] - mean) : 0.f;
                vs += d * d;
            }
#pragma unroll
            for (int off = 32; off > 0; off >>= 1) vs += __shfl_xor(vs, off, 64);
            const float rstd = rsqrtf(vs * (1.0f / OUTF) + EPSL);

            const size_t off0 = isk ? (size_t)OFF_HK + (size_t)(g - M1) * OUTF
                                    : (size_t)g * OUTF;
            float sc = 0.f;
#pragma unroll
            for (int m = 0; m < 5; ++m) {
                int c = lane + 64 * m;
                if (c < OUTF) {
                    float h = (tv[m] - mean) * rstd * gamma[c] + beta[c];
                    out[off0 + c] = h;
                    sc += h * Wsc[c];
                }
            }
#pragma unroll
            for (int off = 32; off > 0; off >>= 1) sc += __shfl_xor(sc, off, 64);
            if (lane == 0) scores[g] = sc + bs0;
        }
    }
}

// ---------------------------------------------------------------------------
// Masked softmax: 128 waves (32 blocks).  Waves 0..63: branch1 row -> probs ws.
// Waves 64..127: know row -> sk written directly to out.
__global__ __launch_bounds__(256)
void softmax_kernel(const float* __restrict__ scores,
                    const void* __restrict__ m1,
                    const void* __restrict__ mk,
                    const int* __restrict__ flagp,
                    float* __restrict__ probs,
                    float* __restrict__ out) {
    const int flag = *flagp;
    const int w = blockIdx.x * 4 + (threadIdx.x >> 6);
    const int lane = threadIdx.x & 63;

    if (w < NB) {
        const int n = w;
        float v0 = scores[n * L1S + lane];
        float v1 = scores[n * L1S + lane + 64];
        if (mask_at(m1, n * L1S + lane, flag))      v0 = -INFINITY;
        if (mask_at(m1, n * L1S + lane + 64, flag)) v1 = -INFINITY;
        float mx = fmaxf(v0, v1);
#pragma unroll
        for (int off = 32; off > 0; off >>= 1) mx = fmaxf(mx, __shfl_xor(mx, off, 64));
        float e0 = __expf(v0 - mx);
        float e1 = __expf(v1 - mx);
        float s = e0 + e1;
#pragma unroll
        for (int off = 32; off > 0; off >>= 1) s += __shfl_xor(s, off, 64);
        float inv = 1.0f / s;
        probs[n * L1S + lane]      = e0 * inv;
        probs[n * L1S + lane + 64] = e1 * inv;
    } else {
        const int n = w - NB;
        float v = -INFINITY;
        if (lane < KS) {
            v = scores[M1 + n * KS + lane];
            if (mask_at(mk, n * KS + lane, flag)) v = -INFINITY;
        }
        float mx = v;
#pragma unroll
        for (int off = 32; off > 0; off >>= 1) mx = fmaxf(mx, __shfl_xor(mx, off, 64));
        float e = (lane < KS) ? __expf(v - mx) : 0.f;
        float s = e;
#pragma unroll
        for (int off = 32; off > 0; off >>= 1) s += __shfl_xor(s, off, 64);
        if (lane < KS) out[(size_t)OFF_SK + n * KS + lane] = e / s;
    }
}

// ---------------------------------------------------------------------------
// Broadcast probs (64x128) -> out score region (64,128,300), float4 writes.
__global__ __launch_bounds__(256)
void bcast_kernel(const float* __restrict__ probs, float* __restrict__ out) {
    const int e0 = (blockIdx.x * 256 + threadIdx.x) * 4;   // 2400 blocks exact
    float4 v;
    v.x = probs[(e0 + 0) / OUTF];
    v.y = probs[(e0 + 1) / OUTF];
    v.z = probs[(e0 + 2) / OUTF];
    v.w = probs[(e0 + 3) / OUTF];
    *(float4*)(out + (size_t)OFF_SCORE + e0) = v;
}

// ---------------------------------------------------------------------------
extern "C" void kernel_launch(void* const* d_in, const int* in_sizes, int n_in,
                              void* d_out, int out_size, void* d_ws, size_t ws_size,
                              hipStream_t stream) {
    const float* t1   = (const float*)d_in[0];
    const float* know = (const float*)d_in[1];
    const int* s1s = (const int*)d_in[2];
    const int* s1e = (const int*)d_in[3];
    const void* m1 = d_in[4];
    const int* kss = (const int*)d_in[5];
    const int* kse = (const int*)d_in[6];
    const void* mk = d_in[7];
    const float* Wl  = (const float*)d_in[8];
    const float* bl  = (const float*)d_in[9];
    const float* gm  = (const float*)d_in[10];
    const float* bt  = (const float*)d_in[11];
    const float* Wsc = (const float*)d_in[12];
    const float* bsc = (const float*)d_in[13];
    float* out = (float*)d_out;

    char* ws = (char*)d_ws;
    int*            flag   = (int*)(ws + WS_FLAG);
    float*          scores = (float*)(ws + WS_SCORES);
    float*          probs  = (float*)(ws + WS_PROBS);
    unsigned short* Wb     = (unsigned short*)(ws + WS_WBF);

    detect_mask_kernel<<<1, 256, 0, stream>>>((const unsigned int*)m1, flag);
    wconv_kernel<<<(NPAD * DIN + 255) / 256, 256, 0, stream>>>(Wl, Wb);
    fused_gemm_kernel<<<MT / 16, 640, 0, stream>>>(t1, know, s1s, s1e, kss, kse,
                                                   Wb, bl, gm, bt, Wsc, bsc,
                                                   out, scores);
    softmax_kernel<<<32, 256, 0, stream>>>(scores, m1, mk, flag, probs, out);
    bcast_kernel<<<(M1 * OUTF) / 1024, 256, 0, stream>>>(probs, out);
}